// Round 5
// baseline (176.833 us; speedup 1.0000x reference)
//
#include <hip/hip_runtime.h>
#include <math.h>

constexpr int B  = 8;
constexpr int C  = 256;
constexpr int L  = 16384;
constexpr int CH = 64;    // c = C/4
constexpr int NB = 256;   // L / BL

typedef __attribute__((ext_vector_type(8))) short bf16x8;
typedef __attribute__((ext_vector_type(4))) float f32x4;

__device__ __forceinline__ unsigned short f2bf(float f) {
    unsigned u = __builtin_bit_cast(unsigned, f);
    u += 0x7fffu + ((u >> 16) & 1u);          // round-to-nearest-even
    return (unsigned short)(u >> 16);
}

__device__ __forceinline__ f32x4 mfma16(bf16x8 a, bf16x8 b, f32x4 c) {
    return __builtin_amdgcn_mfma_f32_16x16x32_bf16(a, b, c, 0, 0, 0);
}

__device__ __forceinline__ bf16x8 pack8(const float* __restrict__ p) {
    float4 f0 = *(const float4*)p;
    float4 f1 = *(const float4*)(p + 4);
    bf16x8 r;
    r[0] = (short)f2bf(f0.x); r[1] = (short)f2bf(f0.y);
    r[2] = (short)f2bf(f0.z); r[3] = (short)f2bf(f0.w);
    r[4] = (short)f2bf(f1.x); r[5] = (short)f2bf(f1.y);
    r[6] = (short)f2bf(f1.z); r[7] = (short)f2bf(f1.w);
    return r;
}

// ---------------------------------------------------------------------------
// Kernel 1: q/k/v projections via MFMA.  grid (L/64, B), block 256 (4 waves).
// A = W stripe (wave w: och w*16..w*16+15), held as register fragments.
// B = x tile staged in LDS as [pos][c] bf16, quad^(pos&7) swizzled.
// Outputs: q,k transposed [b][pos][och] bf16;  v natural [b][och][pos] bf16.
// ---------------------------------------------------------------------------
__global__ __launch_bounds__(256) void qkv_mfma(
    const float* __restrict__ x1, const float* __restrict__ x2,
    const float* __restrict__ Wq, const float* __restrict__ bq,
    const float* __restrict__ Wk, const float* __restrict__ bk,
    const float* __restrict__ Wv, const float* __restrict__ bv,
    unsigned short* __restrict__ qt, unsigned short* __restrict__ kt,
    unsigned short* __restrict__ vt)
{
    __shared__ unsigned short xs[2][64 * 256];   // 2 x 32KB, [pos][c] swizzled
    const int t    = threadIdx.x;
    const int b    = blockIdx.y;
    const int pos0 = blockIdx.x * 64;
    const int lane = t & 63;
    const int w    = t >> 6;
    const int g    = lane >> 4;
    const int l15  = lane & 15;

    // ---- A fragments (W rows) + biases ----
    const int arow = w * 16 + l15;
    bf16x8 aq[8], ak[8], av[8];
#pragma unroll
    for (int s = 0; s < 8; ++s) {
        const int cb = s * 32 + g * 8;
        aq[s] = pack8(Wq + arow * 256 + cb);
        ak[s] = pack8(Wk + arow * 256 + cb);
        av[s] = pack8(Wv + arow * 256 + cb);
    }
    const f32x4 bq4 = *(const f32x4*)(bq + w * 16 + g * 4);
    const f32x4 bk4 = *(const f32x4*)(bk + w * 16 + g * 4);
    const f32x4 bv4 = *(const f32x4*)(bv + w * 16 + g * 4);

    // ---- stage x1, x2: fp32 [c][pos] -> bf16 LDS [pos][c] swizzled ----
    {
        const int p2  = (t & 31) * 2;   // pos pair
        const int cp0 = t >> 5;         // c-pair 0..7 (+8/iter)
#pragma unroll
        for (int xi = 0; xi < 2; ++xi) {
            const float* xb = (xi ? x2 : x1) + (size_t)b * C * L + pos0;
            char* dst = (char*)xs[xi];
#pragma unroll
            for (int it = 0; it < 16; ++it) {
                const int cp = cp0 + it * 8;
                const int c0 = cp * 2;
                const float2 fa = *(const float2*)(xb + (size_t)c0 * L + p2);
                const float2 fb = *(const float2*)(xb + (size_t)(c0 + 1) * L + p2);
                const unsigned w0 = (unsigned)f2bf(fa.x) | ((unsigned)f2bf(fb.x) << 16);
                const unsigned w1 = (unsigned)f2bf(fa.y) | ((unsigned)f2bf(fb.y) << 16);
                const int quad = cp >> 2, inner = (cp & 3) * 4;
                *(unsigned*)(dst + p2 * 512 + ((quad ^ (p2 & 7)) << 4) + inner) = w0;
                *(unsigned*)(dst + (p2 + 1) * 512 + ((quad ^ ((p2 + 1) & 7)) << 4) + inner) = w1;
            }
        }
    }
    __syncthreads();

    // ---- MFMA over 4 pos sub-tiles ----
#pragma unroll 1
    for (int nt = 0; nt < 4; ++nt) {
        f32x4 accq = {0.f, 0.f, 0.f, 0.f}, acck = accq, accv = accq;
        const int prow = nt * 16 + l15;
        const int rswz = prow & 7;
#pragma unroll
        for (int s = 0; s < 8; ++s) {
            const int byo = prow * 512 + (((s * 4 + g) ^ rswz) << 4);
            const bf16x8 bx1 = *(const bf16x8*)((char*)xs[0] + byo);
            const bf16x8 bx2 = *(const bf16x8*)((char*)xs[1] + byo);
            accq = mfma16(aq[s], bx1, accq);
            acck = mfma16(ak[s], bx1, acck);
            accv = mfma16(av[s], bx2, accv);
        }
        const int pos = pos0 + nt * 16 + l15;
        // q, k transposed: [b][pos][och], 4 consecutive och per lane -> 8B store
        {
            uint2 val;
            val.x = (unsigned)f2bf(accq[0] + bq4[0]) | ((unsigned)f2bf(accq[1] + bq4[1]) << 16);
            val.y = (unsigned)f2bf(accq[2] + bq4[2]) | ((unsigned)f2bf(accq[3] + bq4[3]) << 16);
            *(uint2*)(qt + ((size_t)b * L + pos) * 64 + w * 16 + g * 4) = val;
        }
        {
            uint2 val;
            val.x = (unsigned)f2bf(acck[0] + bk4[0]) | ((unsigned)f2bf(acck[1] + bk4[1]) << 16);
            val.y = (unsigned)f2bf(acck[2] + bk4[2]) | ((unsigned)f2bf(acck[3] + bk4[3]) << 16);
            *(uint2*)(kt + ((size_t)b * L + pos) * 64 + w * 16 + g * 4) = val;
        }
        // v natural: [b][och][pos]
#pragma unroll
        for (int r = 0; r < 4; ++r)
            vt[((size_t)b * CH + w * 16 + g * 4 + r) * L + pos] = f2bf(accv[r] + bv4[r]);
    }
}

// ---------------------------------------------------------------------------
// Kernel 2: windowed attention, all-MFMA.  grid 2048 (i = n*8 + b), block 256.
// q from scrambled (bqi=i>>8, nqi=i&255).
// LDS (64KB): qs [64l][64c], ks2 [128j][64c], vs [64c][128j],
//             ps [64l][128j], aos [64l][64c] — all bf16, quad^(row&7) swizzle.
// ---------------------------------------------------------------------------
__global__ __launch_bounds__(256) void attn_mfma(
    const unsigned short* __restrict__ qt, const unsigned short* __restrict__ kt,
    const unsigned short* __restrict__ vt, const float* __restrict__ mask,
    const float* __restrict__ Wo, const float* __restrict__ bo,
    float* __restrict__ outp)
{
    __shared__ unsigned short qs [64 * 64];
    __shared__ unsigned short ks2[128 * 64];
    __shared__ unsigned short vs [64 * 128];
    __shared__ unsigned short ps [64 * 128];
    __shared__ unsigned short aos[64 * 64];

    const int i   = blockIdx.x;
    const int b   = i & 7;
    const int n   = i >> 3;
    const int bqi = i >> 8;
    const int nqi = i & 255;
    const int t    = threadIdx.x;
    const int lane = t & 63;
    const int w    = t >> 6;
    const int g    = lane >> 4;
    const int l15  = lane & 15;
    const int jbase = n * 64 - 64;

    // ---- stage q (64 rows x 128B) ----
    {
        const char* src = (const char*)(qt + ((size_t)bqi * L + nqi * 64) * 64);
#pragma unroll
        for (int it = 0; it < 2; ++it) {
            const int row = (t >> 3) + it * 32, ch = t & 7;
            uint4 d = *(const uint4*)(src + row * 128 + ch * 16);
            *(uint4*)((char*)qs + row * 128 + ((ch ^ (row & 7)) << 4)) = d;
        }
    }
    // ---- stage k window (128 rows x 128B), zero pad rows for n==0 ----
    {
#pragma unroll
        for (int it = 0; it < 4; ++it) {
            const int row = (t >> 3) + it * 32, ch = t & 7;
            uint4 d = make_uint4(0u, 0u, 0u, 0u);
            if (!(n == 0 && row < 64))
                d = *(const uint4*)((const char*)(kt + ((size_t)b * L + jbase + row) * 64) + ch * 16);
            *(uint4*)((char*)ks2 + row * 128 + ((ch ^ (row & 7)) << 4)) = d;
        }
    }
    // ---- stage v window (64 rows x 256B), zero first-half cols for n==0 ----
    {
#pragma unroll
        for (int it = 0; it < 4; ++it) {
            const int row = (t >> 4) + it * 16, ch = t & 15;
            uint4 d = make_uint4(0u, 0u, 0u, 0u);
            if (!(n == 0 && ch < 8))
                d = *(const uint4*)((const char*)(vt + ((size_t)b * CH + row) * L + jbase) + ch * 16);
            *(uint4*)((char*)vs + row * 256 + ((ch ^ (row & 7)) << 4)) = d;
        }
    }
    __syncthreads();

    // ---- E = q^T k : per wave l-strip w*16..+15, all 128 j ----
    f32x4 ae[8];
#pragma unroll
    for (int jt = 0; jt < 8; ++jt) ae[jt] = (f32x4){0.f, 0.f, 0.f, 0.f};
    bf16x8 qa[2];
#pragma unroll
    for (int ks = 0; ks < 2; ++ks) {
        const int row = w * 16 + l15;
        qa[ks] = *(const bf16x8*)((char*)qs + row * 128 + (((ks * 4 + g) ^ (row & 7)) << 4));
    }
#pragma unroll
    for (int jt = 0; jt < 8; ++jt) {
#pragma unroll
        for (int ks = 0; ks < 2; ++ks) {
            const int row = jt * 16 + l15;
            const bf16x8 kb = *(const bf16x8*)((char*)ks2 + row * 128 + (((ks * 4 + g) ^ (row & 7)) << 4));
            ae[jt] = mfma16(qa[ks], kb, ae[jt]);
        }
    }

    // ---- softmax: e = E/8 + log(fm+1e-6); row = (w*16 + 4g + r), col j ----
    const float* mrow = mask + (size_t)b * L + jbase;
    float pw8[8];
#pragma unroll
    for (int jt = 0; jt < 8; ++jt) {
        const int j = l15 + jt * 16;
        pw8[jt] = (n == 0 && j < 64) ? 0.f : mrow[j];
    }
    const int ii0 = w * 16 + g * 4;   // query index base (+r)
#pragma unroll
    for (int jt = 0; jt < 8; ++jt) {
        const int j = l15 + jt * 16;
#pragma unroll
        for (int r = 0; r < 4; ++r) {
            const float fm = (j >= ii0 + r && j < ii0 + r + 64) ? pw8[jt] : 0.f;
            ae[jt][r] = ae[jt][r] * 0.125f + __logf(fm + 1e-6f);
        }
    }
    f32x4 mx, inv;
#pragma unroll
    for (int r = 0; r < 4; ++r) {
        float m = ae[0][r];
#pragma unroll
        for (int jt = 1; jt < 8; ++jt) m = fmaxf(m, ae[jt][r]);
        m = fmaxf(m, __shfl_xor(m, 1));
        m = fmaxf(m, __shfl_xor(m, 2));
        m = fmaxf(m, __shfl_xor(m, 4));
        m = fmaxf(m, __shfl_xor(m, 8));
        mx[r] = m;
    }
    f32x4 sum = {0.f, 0.f, 0.f, 0.f};
#pragma unroll
    for (int jt = 0; jt < 8; ++jt)
#pragma unroll
        for (int r = 0; r < 4; ++r) {
            const float p = __expf(ae[jt][r] - mx[r]);
            ae[jt][r] = p;
            sum[r] += p;
        }
#pragma unroll
    for (int r = 0; r < 4; ++r) {
        float s = sum[r];
        s += __shfl_xor(s, 1);
        s += __shfl_xor(s, 2);
        s += __shfl_xor(s, 4);
        s += __shfl_xor(s, 8);
        inv[r] = 1.0f / s;
    }
    // write att bf16 -> ps[l][j]
#pragma unroll
    for (int jt = 0; jt < 8; ++jt) {
        const int j = l15 + jt * 16;
#pragma unroll
        for (int r = 0; r < 4; ++r) {
            const float fm = (j >= ii0 + r && j < ii0 + r + 64) ? pw8[jt] : 0.f;
            const float p = ae[jt][r] * inv[r] * fm;
            const int lrow = w * 16 + g * 4 + r;
            *(unsigned short*)((char*)ps + lrow * 256 +
                (((j >> 3) ^ (lrow & 7)) << 4) + (j & 7) * 2) = f2bf(p);
        }
    }

    // ---- AO^T[l][c] = att[l][:] x v[c][:] ----
    f32x4 ao[4];
#pragma unroll
    for (int ct = 0; ct < 4; ++ct) ao[ct] = (f32x4){0.f, 0.f, 0.f, 0.f};
#pragma unroll
    for (int ks = 0; ks < 4; ++ks) {
        const int arow = w * 16 + l15;
        const int aq_ = ks * 4 + g;
        const bf16x8 pa = *(const bf16x8*)((char*)ps + arow * 256 + ((aq_ ^ (arow & 7)) << 4));
#pragma unroll
        for (int ct = 0; ct < 4; ++ct) {
            const int vrow = ct * 16 + l15;
            const bf16x8 vb = *(const bf16x8*)((char*)vs + vrow * 256 + ((aq_ ^ (vrow & 7)) << 4));
            ao[ct] = mfma16(pa, vb, ao[ct]);
        }
    }
    // relu -> aos[l][c] bf16
#pragma unroll
    for (int ct = 0; ct < 4; ++ct)
#pragma unroll
        for (int r = 0; r < 4; ++r) {
            const int lr = w * 16 + g * 4 + r;
            const int c  = ct * 16 + l15;
            *(unsigned short*)((char*)aos + lr * 128 +
                (((c >> 3) ^ (lr & 7)) << 4) + (c & 7) * 2) = f2bf(fmaxf(ao[ct][r], 0.f));
        }
    __syncthreads();

    // ---- out = Wo @ relu(AO) + bo, * mask ----
    f32x4 mvv;
#pragma unroll
    for (int lt = 0; lt < 4; ++lt)
        mvv[lt] = mask[(size_t)b * L + n * 64 + lt * 16 + l15];

    bf16x8 bbs[8];   // B fragments: [ks*4+lt]
#pragma unroll
    for (int ks = 0; ks < 2; ++ks)
#pragma unroll
        for (int lt = 0; lt < 4; ++lt) {
            const int brow = lt * 16 + l15;
            bbs[ks * 4 + lt] = *(const bf16x8*)((char*)aos + brow * 128 +
                (((ks * 4 + g) ^ (brow & 7)) << 4));
        }

#pragma unroll 1
    for (int ot = 0; ot < 4; ++ot) {
        const int orow = ot * 64 + w * 16 + l15;
        bf16x8 wa[2];
#pragma unroll
        for (int ks = 0; ks < 2; ++ks)
            wa[ks] = pack8(Wo + (size_t)orow * 64 + ks * 32 + g * 8);
        f32x4 acw[4];
#pragma unroll
        for (int lt = 0; lt < 4; ++lt) acw[lt] = (f32x4){0.f, 0.f, 0.f, 0.f};
#pragma unroll
        for (int ks = 0; ks < 2; ++ks)
#pragma unroll
            for (int lt = 0; lt < 4; ++lt)
                acw[lt] = mfma16(wa[ks], bbs[ks * 4 + lt], acw[lt]);
        const f32x4 bo4 = *(const f32x4*)(bo + ot * 64 + w * 16 + g * 4);
#pragma unroll
        for (int lt = 0; lt < 4; ++lt) {
            const int pos = n * 64 + lt * 16 + l15;
#pragma unroll
            for (int r = 0; r < 4; ++r) {
                const int o = ot * 64 + w * 16 + g * 4 + r;
                outp[((size_t)b * C + o) * L + pos] = (acw[lt][r] + bo4[r]) * mvv[lt];
            }
        }
    }
}

// ---------------------------------------------------------------------------
extern "C" void kernel_launch(void* const* d_in, const int* in_sizes, int n_in,
                              void* d_out, int out_size, void* d_ws, size_t ws_size,
                              hipStream_t stream) {
    const float* x1   = (const float*)d_in[0];
    const float* x2   = (const float*)d_in[1];
    const float* mask = (const float*)d_in[2];
    const float* Wq   = (const float*)d_in[3];
    const float* bq   = (const float*)d_in[4];
    const float* Wk   = (const float*)d_in[5];
    const float* bk   = (const float*)d_in[6];
    const float* Wv   = (const float*)d_in[7];
    const float* bv   = (const float*)d_in[8];
    const float* Wo   = (const float*)d_in[9];
    const float* bo   = (const float*)d_in[10];
    float* out = (float*)d_out;

    unsigned short* qt = (unsigned short*)d_ws;
    unsigned short* kt = qt + (size_t)B * L * CH;
    unsigned short* vt = kt + (size_t)B * L * CH;
    const size_t need = 3ull * B * L * CH * sizeof(unsigned short);
    if (ws_size < need) {
        hipMemsetAsync(d_out, 0, (size_t)out_size * sizeof(float), stream);
        return;
    }

    qkv_mfma<<<dim3(L / 64, B), 256, 0, stream>>>(
        x1, x2, Wq, bq, Wk, bk, Wv, bv, qt, kt, vt);

    attn_mfma<<<dim3(NB * B), 256, 0, stream>>>(
        qt, kt, vt, mask, Wo, bo, out);
}

// Round 6
// 136.331 us; speedup vs baseline: 1.2971x; 1.2971x over previous
//
#include <hip/hip_runtime.h>
#include <hip/hip_bf16.h>
#include <math.h>

constexpr int B  = 8;
constexpr int C  = 256;
constexpr int L  = 16384;
constexpr int CH = 64;    // c = C/4
constexpr int NB = 256;   // L / BL

typedef __attribute__((ext_vector_type(8))) short bf16x8;
typedef __attribute__((ext_vector_type(4))) float f32x4;

__device__ __forceinline__ unsigned short f2bfu(float f) {
    __hip_bfloat16 h = __float2bfloat16(f);   // RNE, HW v_cvt
    return __builtin_bit_cast(unsigned short, h);
}
__device__ __forceinline__ unsigned pk2(float lo, float hi) {
    return (unsigned)f2bfu(lo) | ((unsigned)f2bfu(hi) << 16);
}
__device__ __forceinline__ f32x4 mfma16(bf16x8 a, bf16x8 b, f32x4 c) {
    return __builtin_amdgcn_mfma_f32_16x16x32_bf16(a, b, c, 0, 0, 0);
}
// Gray-ish row hash: all 8 values over 8 consecutive EVEN rows and over 8
// consecutive rows -> conflict-free b128 writes, 2-way (free) b128 reads.
__device__ __forceinline__ int hsh(int r) { return (r ^ (r >> 1)) & 7; }

// ---------------------------------------------------------------------------
// Kernel 0: convert Wq,Wk,Wv,Wo (each 16384 fp32) to bf16 once.
// ---------------------------------------------------------------------------
__global__ __launch_bounds__(256) void wcvt_kernel(
    const float* __restrict__ Wq, const float* __restrict__ Wk,
    const float* __restrict__ Wv, const float* __restrict__ Wo,
    unsigned short* __restrict__ dst)   // [4][16384]
{
    const int z = blockIdx.y;
    const float* src = (z == 0) ? Wq : (z == 1) ? Wk : (z == 2) ? Wv : Wo;
    const int i = (blockIdx.x * 256 + threadIdx.x) * 4;
    float4 f = *(const float4*)(src + i);
    uint2 v;
    v.x = pk2(f.x, f.y);
    v.y = pk2(f.z, f.w);
    *(uint2*)(dst + (size_t)z * 16384 + i) = v;
}

// ---------------------------------------------------------------------------
// Stage one 64pos x 256c fp32 tile -> bf16 LDS [pos][c], hash-swizzled.
// Lane: rows p2,p2+1; per it 8 c-rows -> two b128 writes (conflict-free).
// ---------------------------------------------------------------------------
__device__ __forceinline__ void stage_x(const float* __restrict__ xb,
                                        unsigned short* __restrict__ xs,
                                        int p2, int g8, int h0, int h1)
{
    char* dst = (char*)xs;
#pragma unroll
    for (int it = 0; it < 4; ++it) {
        const int cblk = g8 + it * 8;             // c = cblk*8 + cc
        const float* base = xb + (size_t)(cblk * 8) * L + p2;
        float2 f[8];
#pragma unroll
        for (int cc = 0; cc < 8; ++cc)
            f[cc] = *(const float2*)(base + (size_t)cc * L);
        uint4 r0, r1;
        r0.x = pk2(f[0].x, f[1].x); r0.y = pk2(f[2].x, f[3].x);
        r0.z = pk2(f[4].x, f[5].x); r0.w = pk2(f[6].x, f[7].x);
        r1.x = pk2(f[0].y, f[1].y); r1.y = pk2(f[2].y, f[3].y);
        r1.z = pk2(f[4].y, f[5].y); r1.w = pk2(f[6].y, f[7].y);
        *(uint4*)(dst + p2 * 512 + ((cblk ^ h0) << 4)) = r0;
        *(uint4*)(dst + (p2 + 1) * 512 + ((cblk ^ h1) << 4)) = r1;
    }
}

// ---------------------------------------------------------------------------
// Kernel 1: q/k/v projections via MFMA.  grid (L/64, B), block 256 (4 waves).
// Sequential phases share ONE 32KB x-buffer: x1 -> q,k; then x2 -> v.
// Outputs: q,k transposed [b][pos][och] bf16;  v natural [b][och][pos] bf16.
// ---------------------------------------------------------------------------
__global__ __launch_bounds__(256, 4) void qkv_mfma(
    const float* __restrict__ x1, const float* __restrict__ x2,
    const unsigned short* __restrict__ wqb, const unsigned short* __restrict__ wkb,
    const unsigned short* __restrict__ wvb,
    const float* __restrict__ bq, const float* __restrict__ bk,
    const float* __restrict__ bv,
    unsigned short* __restrict__ qt, unsigned short* __restrict__ kt,
    unsigned short* __restrict__ vt)
{
    __shared__ unsigned short xs[64 * 256];   // 32KB [pos][c] swizzled
    const int t    = threadIdx.x;
    const int b    = blockIdx.y;
    const int pos0 = blockIdx.x * 64;
    const int lane = t & 63;
    const int w    = t >> 6;
    const int g    = lane >> 4;
    const int l15  = lane & 15;
    const int p2   = (t & 31) * 2;
    const int g8   = t >> 5;
    const int h0   = hsh(p2), h1 = hsh(p2 + 1);
    const int arow = w * 16 + l15;

    // ---------- phase 1: x1 -> q, k ----------
    stage_x(x1 + (size_t)b * C * L + pos0, xs, p2, g8, h0, h1);
    bf16x8 aq[8], ak[8];
#pragma unroll
    for (int s = 0; s < 8; ++s) {
        aq[s] = *(const bf16x8*)(wqb + arow * 256 + s * 32 + g * 8);
        ak[s] = *(const bf16x8*)(wkb + arow * 256 + s * 32 + g * 8);
    }
    const f32x4 bq4 = *(const f32x4*)(bq + w * 16 + g * 4);
    const f32x4 bk4 = *(const f32x4*)(bk + w * 16 + g * 4);
    __syncthreads();

#pragma unroll
    for (int nt = 0; nt < 4; ++nt) {
        f32x4 accq = {0.f, 0.f, 0.f, 0.f}, acck = accq;
        const int prow = nt * 16 + l15;
        const int rh = hsh(prow);
#pragma unroll
        for (int s = 0; s < 8; ++s) {
            const bf16x8 bx = *(const bf16x8*)((char*)xs + prow * 512 +
                                               (((s * 4 + g) ^ rh) << 4));
            accq = mfma16(aq[s], bx, accq);
            acck = mfma16(ak[s], bx, acck);
        }
        const int pos = pos0 + nt * 16 + l15;
        uint2 vq, vk;
        vq.x = pk2(accq[0] + bq4[0], accq[1] + bq4[1]);
        vq.y = pk2(accq[2] + bq4[2], accq[3] + bq4[3]);
        *(uint2*)(qt + ((size_t)b * L + pos) * 64 + w * 16 + g * 4) = vq;
        vk.x = pk2(acck[0] + bk4[0], acck[1] + bk4[1]);
        vk.y = pk2(acck[2] + bk4[2], acck[3] + bk4[3]);
        *(uint2*)(kt + ((size_t)b * L + pos) * 64 + w * 16 + g * 4) = vk;
    }
    __syncthreads();   // all phase-1 LDS reads done before restage

    // ---------- phase 2: x2 -> v ----------
    stage_x(x2 + (size_t)b * C * L + pos0, xs, p2, g8, h0, h1);
    bf16x8 av[8];
#pragma unroll
    for (int s = 0; s < 8; ++s)
        av[s] = *(const bf16x8*)(wvb + arow * 256 + s * 32 + g * 8);
    const f32x4 bv4 = *(const f32x4*)(bv + w * 16 + g * 4);
    __syncthreads();

#pragma unroll
    for (int nt = 0; nt < 4; ++nt) {
        f32x4 accv = {0.f, 0.f, 0.f, 0.f};
        const int prow = nt * 16 + l15;
        const int rh = hsh(prow);
#pragma unroll
        for (int s = 0; s < 8; ++s) {
            const bf16x8 bx = *(const bf16x8*)((char*)xs + prow * 512 +
                                               (((s * 4 + g) ^ rh) << 4));
            accv = mfma16(av[s], bx, accv);
        }
        const int pos = pos0 + nt * 16 + l15;
#pragma unroll
        for (int r = 0; r < 4; ++r)
            vt[((size_t)b * CH + w * 16 + g * 4 + r) * L + pos] = f2bfu(accv[r] + bv4[r]);
    }
}

// ---------------------------------------------------------------------------
// Kernel 2: windowed attention, all-MFMA.  grid 2048 (i = n*8 + b), block 256.
// q from scrambled (bqi=i>>8, nqi=i&255).  (unchanged from round 5 except
// bf16 Wo and 1-op bf16 converts)
// ---------------------------------------------------------------------------
__global__ __launch_bounds__(256) void attn_mfma(
    const unsigned short* __restrict__ qt, const unsigned short* __restrict__ kt,
    const unsigned short* __restrict__ vt, const float* __restrict__ mask,
    const unsigned short* __restrict__ wob, const float* __restrict__ bo,
    float* __restrict__ outp)
{
    __shared__ unsigned short qs [64 * 64];
    __shared__ unsigned short ks2[128 * 64];
    __shared__ unsigned short vs [64 * 128];
    __shared__ unsigned short ps [64 * 128];
    __shared__ unsigned short aos[64 * 64];

    const int i   = blockIdx.x;
    const int b   = i & 7;
    const int n   = i >> 3;
    const int bqi = i >> 8;
    const int nqi = i & 255;
    const int t    = threadIdx.x;
    const int lane = t & 63;
    const int w    = t >> 6;
    const int g    = lane >> 4;
    const int l15  = lane & 15;
    const int jbase = n * 64 - 64;

    // ---- stage q (64 rows x 128B) ----
    {
        const char* src = (const char*)(qt + ((size_t)bqi * L + nqi * 64) * 64);
#pragma unroll
        for (int it = 0; it < 2; ++it) {
            const int row = (t >> 3) + it * 32, ch = t & 7;
            uint4 d = *(const uint4*)(src + row * 128 + ch * 16);
            *(uint4*)((char*)qs + row * 128 + ((ch ^ (row & 7)) << 4)) = d;
        }
    }
    // ---- stage k window (128 rows x 128B), zero pad rows for n==0 ----
    {
#pragma unroll
        for (int it = 0; it < 4; ++it) {
            const int row = (t >> 3) + it * 32, ch = t & 7;
            uint4 d = make_uint4(0u, 0u, 0u, 0u);
            if (!(n == 0 && row < 64))
                d = *(const uint4*)((const char*)(kt + ((size_t)b * L + jbase + row) * 64) + ch * 16);
            *(uint4*)((char*)ks2 + row * 128 + ((ch ^ (row & 7)) << 4)) = d;
        }
    }
    // ---- stage v window (64 rows x 256B), zero first-half cols for n==0 ----
    {
#pragma unroll
        for (int it = 0; it < 4; ++it) {
            const int row = (t >> 4) + it * 16, ch = t & 15;
            uint4 d = make_uint4(0u, 0u, 0u, 0u);
            if (!(n == 0 && ch < 8))
                d = *(const uint4*)((const char*)(vt + ((size_t)b * CH + row) * L + jbase) + ch * 16);
            *(uint4*)((char*)vs + row * 256 + ((ch ^ (row & 7)) << 4)) = d;
        }
    }
    __syncthreads();

    // ---- E = q^T k ----
    f32x4 ae[8];
#pragma unroll
    for (int jt = 0; jt < 8; ++jt) ae[jt] = (f32x4){0.f, 0.f, 0.f, 0.f};
    bf16x8 qa[2];
#pragma unroll
    for (int ks = 0; ks < 2; ++ks) {
        const int row = w * 16 + l15;
        qa[ks] = *(const bf16x8*)((char*)qs + row * 128 + (((ks * 4 + g) ^ (row & 7)) << 4));
    }
#pragma unroll
    for (int jt = 0; jt < 8; ++jt) {
#pragma unroll
        for (int ks = 0; ks < 2; ++ks) {
            const int row = jt * 16 + l15;
            const bf16x8 kb = *(const bf16x8*)((char*)ks2 + row * 128 + (((ks * 4 + g) ^ (row & 7)) << 4));
            ae[jt] = mfma16(qa[ks], kb, ae[jt]);
        }
    }

    // ---- softmax: e = E/8 + log(fm+1e-6) ----
    const float* mrow = mask + (size_t)b * L + jbase;
    float pw8[8];
#pragma unroll
    for (int jt = 0; jt < 8; ++jt) {
        const int j = l15 + jt * 16;
        pw8[jt] = (n == 0 && j < 64) ? 0.f : mrow[j];
    }
    const int ii0 = w * 16 + g * 4;
#pragma unroll
    for (int jt = 0; jt < 8; ++jt) {
        const int j = l15 + jt * 16;
#pragma unroll
        for (int r = 0; r < 4; ++r) {
            const float fm = (j >= ii0 + r && j < ii0 + r + 64) ? pw8[jt] : 0.f;
            ae[jt][r] = ae[jt][r] * 0.125f + __logf(fm + 1e-6f);
        }
    }
    f32x4 mx, inv;
#pragma unroll
    for (int r = 0; r < 4; ++r) {
        float m = ae[0][r];
#pragma unroll
        for (int jt = 1; jt < 8; ++jt) m = fmaxf(m, ae[jt][r]);
        m = fmaxf(m, __shfl_xor(m, 1));
        m = fmaxf(m, __shfl_xor(m, 2));
        m = fmaxf(m, __shfl_xor(m, 4));
        m = fmaxf(m, __shfl_xor(m, 8));
        mx[r] = m;
    }
    f32x4 sum = {0.f, 0.f, 0.f, 0.f};
#pragma unroll
    for (int jt = 0; jt < 8; ++jt)
#pragma unroll
        for (int r = 0; r < 4; ++r) {
            const float p = __expf(ae[jt][r] - mx[r]);
            ae[jt][r] = p;
            sum[r] += p;
        }
#pragma unroll
    for (int r = 0; r < 4; ++r) {
        float s = sum[r];
        s += __shfl_xor(s, 1);
        s += __shfl_xor(s, 2);
        s += __shfl_xor(s, 4);
        s += __shfl_xor(s, 8);
        inv[r] = 1.0f / s;
    }
#pragma unroll
    for (int jt = 0; jt < 8; ++jt) {
        const int j = l15 + jt * 16;
#pragma unroll
        for (int r = 0; r < 4; ++r) {
            const float fm = (j >= ii0 + r && j < ii0 + r + 64) ? pw8[jt] : 0.f;
            const float p = ae[jt][r] * inv[r] * fm;
            const int lrow = w * 16 + g * 4 + r;
            *(unsigned short*)((char*)ps + lrow * 256 +
                (((j >> 3) ^ (lrow & 7)) << 4) + (j & 7) * 2) = f2bfu(p);
        }
    }

    // ---- AO^T[l][c] = att[l][:] x v[c][:] ----
    f32x4 ao[4];
#pragma unroll
    for (int ct = 0; ct < 4; ++ct) ao[ct] = (f32x4){0.f, 0.f, 0.f, 0.f};
#pragma unroll
    for (int ks = 0; ks < 4; ++ks) {
        const int arow = w * 16 + l15;
        const int aq_ = ks * 4 + g;
        const bf16x8 pa = *(const bf16x8*)((char*)ps + arow * 256 + ((aq_ ^ (arow & 7)) << 4));
#pragma unroll
        for (int ct = 0; ct < 4; ++ct) {
            const int vrow = ct * 16 + l15;
            const bf16x8 vb = *(const bf16x8*)((char*)vs + vrow * 256 + ((aq_ ^ (vrow & 7)) << 4));
            ao[ct] = mfma16(pa, vb, ao[ct]);
        }
    }
#pragma unroll
    for (int ct = 0; ct < 4; ++ct)
#pragma unroll
        for (int r = 0; r < 4; ++r) {
            const int lr = w * 16 + g * 4 + r;
            const int c  = ct * 16 + l15;
            *(unsigned short*)((char*)aos + lr * 128 +
                (((c >> 3) ^ (lr & 7)) << 4) + (c & 7) * 2) = f2bfu(fmaxf(ao[ct][r], 0.f));
        }
    __syncthreads();

    // ---- out = Wo @ relu(AO) + bo, * mask ----
    f32x4 mvv;
#pragma unroll
    for (int lt = 0; lt < 4; ++lt)
        mvv[lt] = mask[(size_t)b * L + n * 64 + lt * 16 + l15];

    bf16x8 bbs[8];
#pragma unroll
    for (int ks = 0; ks < 2; ++ks)
#pragma unroll
        for (int lt = 0; lt < 4; ++lt) {
            const int brow = lt * 16 + l15;
            bbs[ks * 4 + lt] = *(const bf16x8*)((char*)aos + brow * 128 +
                (((ks * 4 + g) ^ (brow & 7)) << 4));
        }

#pragma unroll 1
    for (int ot = 0; ot < 4; ++ot) {
        const int orow = ot * 64 + w * 16 + l15;
        bf16x8 wa[2];
#pragma unroll
        for (int ks = 0; ks < 2; ++ks)
            wa[ks] = *(const bf16x8*)(wob + (size_t)orow * 64 + ks * 32 + g * 8);
        f32x4 acw[4];
#pragma unroll
        for (int lt = 0; lt < 4; ++lt) acw[lt] = (f32x4){0.f, 0.f, 0.f, 0.f};
#pragma unroll
        for (int ks = 0; ks < 2; ++ks)
#pragma unroll
            for (int lt = 0; lt < 4; ++lt)
                acw[lt] = mfma16(wa[ks], bbs[ks * 4 + lt], acw[lt]);
        const f32x4 bo4 = *(const f32x4*)(bo + ot * 64 + w * 16 + g * 4);
#pragma unroll
        for (int lt = 0; lt < 4; ++lt) {
            const int pos = n * 64 + lt * 16 + l15;
#pragma unroll
            for (int r = 0; r < 4; ++r) {
                const int o = ot * 64 + w * 16 + g * 4 + r;
                outp[((size_t)b * C + o) * L + pos] = (acw[lt][r] + bo4[r]) * mvv[lt];
            }
        }
    }
}

// ---------------------------------------------------------------------------
extern "C" void kernel_launch(void* const* d_in, const int* in_sizes, int n_in,
                              void* d_out, int out_size, void* d_ws, size_t ws_size,
                              hipStream_t stream) {
    const float* x1   = (const float*)d_in[0];
    const float* x2   = (const float*)d_in[1];
    const float* mask = (const float*)d_in[2];
    const float* Wq   = (const float*)d_in[3];
    const float* bq   = (const float*)d_in[4];
    const float* Wk   = (const float*)d_in[5];
    const float* bk   = (const float*)d_in[6];
    const float* Wv   = (const float*)d_in[7];
    const float* bv   = (const float*)d_in[8];
    const float* Wo   = (const float*)d_in[9];
    const float* bo   = (const float*)d_in[10];
    float* out = (float*)d_out;

    unsigned short* ws = (unsigned short*)d_ws;
    const size_t PL = (size_t)B * L * CH;
    unsigned short* qt = ws;
    unsigned short* kt = qt + PL;
    unsigned short* vt = kt + PL;
    unsigned short* wb = vt + PL;   // [4][16384] bf16 weights
    const size_t need = (3 * PL + 4 * 16384) * sizeof(unsigned short);
    if (ws_size < need) {
        hipMemsetAsync(d_out, 0, (size_t)out_size * sizeof(float), stream);
        return;
    }

    wcvt_kernel<<<dim3(16, 4), 256, 0, stream>>>(Wq, Wk, Wv, Wo, wb);

    qkv_mfma<<<dim3(L / 64, B), 256, 0, stream>>>(
        x1, x2, wb, wb + 16384, wb + 2 * 16384, bq, bk, bv, qt, kt, vt);

    attn_mfma<<<dim3(NB * B), 256, 0, stream>>>(
        qt, kt, vt, mask, wb + 3 * 16384, bo, out);
}

// Round 7
// 132.818 us; speedup vs baseline: 1.3314x; 1.0265x over previous
//
#include <hip/hip_runtime.h>
#include <hip/hip_bf16.h>
#include <math.h>

constexpr int B  = 8;
constexpr int C  = 256;
constexpr int L  = 16384;
constexpr int CH = 64;    // c = C/4
constexpr int NB = 256;   // L / BL

typedef __attribute__((ext_vector_type(8))) short bf16x8;
typedef __attribute__((ext_vector_type(4))) float f32x4;

__device__ __forceinline__ unsigned short f2bfu(float f) {
    __hip_bfloat16 h = __float2bfloat16(f);   // RNE, HW v_cvt
    return __builtin_bit_cast(unsigned short, h);
}
__device__ __forceinline__ unsigned pk2(float lo, float hi) {
    return (unsigned)f2bfu(lo) | ((unsigned)f2bfu(hi) << 16);
}
__device__ __forceinline__ f32x4 mfma16(bf16x8 a, bf16x8 b, f32x4 c) {
    return __builtin_amdgcn_mfma_f32_16x16x32_bf16(a, b, c, 0, 0, 0);
}
// Gray-ish row hash: conflict-free b128 writes, 2-way (free) b128 reads.
__device__ __forceinline__ int hsh(int r) { return (r ^ (r >> 1)) & 7; }

// ---------------------------------------------------------------------------
// Kernel 0: convert Wq,Wk,Wv,Wo (each 16384 fp32) to bf16 once.
// ---------------------------------------------------------------------------
__global__ __launch_bounds__(256) void wcvt_kernel(
    const float* __restrict__ Wq, const float* __restrict__ Wk,
    const float* __restrict__ Wv, const float* __restrict__ Wo,
    unsigned short* __restrict__ dst)   // [4][16384]
{
    const int z = blockIdx.y;
    const float* src = (z == 0) ? Wq : (z == 1) ? Wk : (z == 2) ? Wv : Wo;
    const int i = (blockIdx.x * 256 + threadIdx.x) * 4;
    float4 f = *(const float4*)(src + i);
    uint2 v;
    v.x = pk2(f.x, f.y);
    v.y = pk2(f.z, f.w);
    *(uint2*)(dst + (size_t)z * 16384 + i) = v;
}

// ---------------------------------------------------------------------------
// Deep-ILP staging: load the WHOLE 64pos x 256c fp32 tile into registers
// (32 independent float2 loads in flight), then convert+write LDS.
// ---------------------------------------------------------------------------
__device__ __forceinline__ void ldx(const float* __restrict__ xb,
                                    int p2, int g8, float2 (&f)[4][8])
{
#pragma unroll
    for (int it = 0; it < 4; ++it) {
        const float* base = xb + (size_t)((g8 + it * 8) * 8) * L + p2;
#pragma unroll
        for (int cc = 0; cc < 8; ++cc)
            f[it][cc] = *(const float2*)(base + (size_t)cc * L);
    }
}
__device__ __forceinline__ void stx(unsigned short* __restrict__ xs,
                                    int p2, int g8, int h0, int h1,
                                    const float2 (&f)[4][8])
{
    char* dst = (char*)xs;
#pragma unroll
    for (int it = 0; it < 4; ++it) {
        const int cblk = g8 + it * 8;
        uint4 r0, r1;
        r0.x = pk2(f[it][0].x, f[it][1].x); r0.y = pk2(f[it][2].x, f[it][3].x);
        r0.z = pk2(f[it][4].x, f[it][5].x); r0.w = pk2(f[it][6].x, f[it][7].x);
        r1.x = pk2(f[it][0].y, f[it][1].y); r1.y = pk2(f[it][2].y, f[it][3].y);
        r1.z = pk2(f[it][4].y, f[it][5].y); r1.w = pk2(f[it][6].y, f[it][7].y);
        *(uint4*)(dst + p2 * 512 + ((cblk ^ h0) << 4)) = r0;
        *(uint4*)(dst + (p2 + 1) * 512 + ((cblk ^ h1) << 4)) = r1;
    }
}

// ---------------------------------------------------------------------------
// Kernel 1: q/k/v projections via MFMA.  grid (L/64, B), block 256 (4 waves).
// Pipeline: ldx(x1) -> stx -> sync -> ldx(x2) [in flight] -> q MFMA -> k MFMA
//           -> sync -> stx(x2) -> sync -> v MFMA.
// Outputs: q,k transposed [b][pos][och] bf16;  v natural [b][och][pos] bf16.
// ---------------------------------------------------------------------------
__global__ __launch_bounds__(256, 3) void qkv_mfma(
    const float* __restrict__ x1, const float* __restrict__ x2,
    const unsigned short* __restrict__ wqb, const unsigned short* __restrict__ wkb,
    const unsigned short* __restrict__ wvb,
    const float* __restrict__ bq, const float* __restrict__ bk,
    const float* __restrict__ bv,
    unsigned short* __restrict__ qt, unsigned short* __restrict__ kt,
    unsigned short* __restrict__ vt)
{
    __shared__ unsigned short xs[64 * 256];   // 32KB [pos][c] swizzled
    const int t    = threadIdx.x;
    const int b    = blockIdx.y;
    const int pos0 = blockIdx.x * 64;
    const int lane = t & 63;
    const int w    = t >> 6;
    const int g    = lane >> 4;
    const int l15  = lane & 15;
    const int p2   = (t & 31) * 2;
    const int g8   = t >> 5;
    const int h0   = hsh(p2), h1 = hsh(p2 + 1);
    const int arow = w * 16 + l15;

    float2 fx[4][8];

    // ---------- stage x1 ----------
    ldx(x1 + (size_t)b * C * L + pos0, p2, g8, fx);
    stx(xs, p2, g8, h0, h1, fx);
    __syncthreads();

    // ---------- prefetch x2 into regs (flies during q,k compute) ----------
    ldx(x2 + (size_t)b * C * L + pos0, p2, g8, fx);

    // ---------- q ----------
    {
        bf16x8 a[8];
#pragma unroll
        for (int s = 0; s < 8; ++s)
            a[s] = *(const bf16x8*)(wqb + arow * 256 + s * 32 + g * 8);
        const f32x4 b4 = *(const f32x4*)(bq + w * 16 + g * 4);
#pragma unroll
        for (int nt = 0; nt < 4; ++nt) {
            f32x4 acc = {0.f, 0.f, 0.f, 0.f};
            const int prow = nt * 16 + l15;
            const int rh = hsh(prow);
#pragma unroll
            for (int s = 0; s < 8; ++s) {
                const bf16x8 bx = *(const bf16x8*)((char*)xs + prow * 512 +
                                                   (((s * 4 + g) ^ rh) << 4));
                acc = mfma16(a[s], bx, acc);
            }
            const int pos = pos0 + nt * 16 + l15;
            uint2 v;
            v.x = pk2(acc[0] + b4[0], acc[1] + b4[1]);
            v.y = pk2(acc[2] + b4[2], acc[3] + b4[3]);
            *(uint2*)(qt + ((size_t)b * L + pos) * 64 + w * 16 + g * 4) = v;
        }
    }
    __builtin_amdgcn_sched_barrier(0);   // keep k-frag loads out of q phase

    // ---------- k ----------
    {
        bf16x8 a[8];
#pragma unroll
        for (int s = 0; s < 8; ++s)
            a[s] = *(const bf16x8*)(wkb + arow * 256 + s * 32 + g * 8);
        const f32x4 b4 = *(const f32x4*)(bk + w * 16 + g * 4);
#pragma unroll
        for (int nt = 0; nt < 4; ++nt) {
            f32x4 acc = {0.f, 0.f, 0.f, 0.f};
            const int prow = nt * 16 + l15;
            const int rh = hsh(prow);
#pragma unroll
            for (int s = 0; s < 8; ++s) {
                const bf16x8 bx = *(const bf16x8*)((char*)xs + prow * 512 +
                                                   (((s * 4 + g) ^ rh) << 4));
                acc = mfma16(a[s], bx, acc);
            }
            const int pos = pos0 + nt * 16 + l15;
            uint2 v;
            v.x = pk2(acc[0] + b4[0], acc[1] + b4[1]);
            v.y = pk2(acc[2] + b4[2], acc[3] + b4[3]);
            *(uint2*)(kt + ((size_t)b * L + pos) * 64 + w * 16 + g * 4) = v;
        }
    }

    __syncthreads();   // all phase-1 LDS reads done before restage
    stx(xs, p2, g8, h0, h1, fx);   // x2 (waits its vmcnt; long satisfied)
    __syncthreads();

    // ---------- v ----------
    {
        bf16x8 a[8];
#pragma unroll
        for (int s = 0; s < 8; ++s)
            a[s] = *(const bf16x8*)(wvb + arow * 256 + s * 32 + g * 8);
        const f32x4 b4 = *(const f32x4*)(bv + w * 16 + g * 4);
#pragma unroll
        for (int nt = 0; nt < 4; ++nt) {
            f32x4 acc = {0.f, 0.f, 0.f, 0.f};
            const int prow = nt * 16 + l15;
            const int rh = hsh(prow);
#pragma unroll
            for (int s = 0; s < 8; ++s) {
                const bf16x8 bx = *(const bf16x8*)((char*)xs + prow * 512 +
                                                   (((s * 4 + g) ^ rh) << 4));
                acc = mfma16(a[s], bx, acc);
            }
            const int pos = pos0 + nt * 16 + l15;
#pragma unroll
            for (int r = 0; r < 4; ++r)
                vt[((size_t)b * CH + w * 16 + g * 4 + r) * L + pos] = f2bfu(acc[r] + b4[r]);
        }
    }
}

// ---------------------------------------------------------------------------
// Kernel 2: windowed attention, all-MFMA.  grid 2048 (i = n*8 + b), block 256.
// q from scrambled (bqi=i>>8, nqi=i&255).  (unchanged from round 6)
// ---------------------------------------------------------------------------
__global__ __launch_bounds__(256) void attn_mfma(
    const unsigned short* __restrict__ qt, const unsigned short* __restrict__ kt,
    const unsigned short* __restrict__ vt, const float* __restrict__ mask,
    const unsigned short* __restrict__ wob, const float* __restrict__ bo,
    float* __restrict__ outp)
{
    __shared__ unsigned short qs [64 * 64];
    __shared__ unsigned short ks2[128 * 64];
    __shared__ unsigned short vs [64 * 128];
    __shared__ unsigned short ps [64 * 128];
    __shared__ unsigned short aos[64 * 64];

    const int i   = blockIdx.x;
    const int b   = i & 7;
    const int n   = i >> 3;
    const int bqi = i >> 8;
    const int nqi = i & 255;
    const int t    = threadIdx.x;
    const int lane = t & 63;
    const int w    = t >> 6;
    const int g    = lane >> 4;
    const int l15  = lane & 15;
    const int jbase = n * 64 - 64;

    // ---- stage q (64 rows x 128B) ----
    {
        const char* src = (const char*)(qt + ((size_t)bqi * L + nqi * 64) * 64);
#pragma unroll
        for (int it = 0; it < 2; ++it) {
            const int row = (t >> 3) + it * 32, ch = t & 7;
            uint4 d = *(const uint4*)(src + row * 128 + ch * 16);
            *(uint4*)((char*)qs + row * 128 + ((ch ^ (row & 7)) << 4)) = d;
        }
    }
    // ---- stage k window (128 rows x 128B), zero pad rows for n==0 ----
    {
#pragma unroll
        for (int it = 0; it < 4; ++it) {
            const int row = (t >> 3) + it * 32, ch = t & 7;
            uint4 d = make_uint4(0u, 0u, 0u, 0u);
            if (!(n == 0 && row < 64))
                d = *(const uint4*)((const char*)(kt + ((size_t)b * L + jbase + row) * 64) + ch * 16);
            *(uint4*)((char*)ks2 + row * 128 + ((ch ^ (row & 7)) << 4)) = d;
        }
    }
    // ---- stage v window (64 rows x 256B), zero first-half cols for n==0 ----
    {
#pragma unroll
        for (int it = 0; it < 4; ++it) {
            const int row = (t >> 4) + it * 16, ch = t & 15;
            uint4 d = make_uint4(0u, 0u, 0u, 0u);
            if (!(n == 0 && ch < 8))
                d = *(const uint4*)((const char*)(vt + ((size_t)b * CH + row) * L + jbase) + ch * 16);
            *(uint4*)((char*)vs + row * 256 + ((ch ^ (row & 7)) << 4)) = d;
        }
    }
    __syncthreads();

    // ---- E = q^T k ----
    f32x4 ae[8];
#pragma unroll
    for (int jt = 0; jt < 8; ++jt) ae[jt] = (f32x4){0.f, 0.f, 0.f, 0.f};
    bf16x8 qa[2];
#pragma unroll
    for (int ks = 0; ks < 2; ++ks) {
        const int row = w * 16 + l15;
        qa[ks] = *(const bf16x8*)((char*)qs + row * 128 + (((ks * 4 + g) ^ (row & 7)) << 4));
    }
#pragma unroll
    for (int jt = 0; jt < 8; ++jt) {
#pragma unroll
        for (int ks = 0; ks < 2; ++ks) {
            const int row = jt * 16 + l15;
            const bf16x8 kb = *(const bf16x8*)((char*)ks2 + row * 128 + (((ks * 4 + g) ^ (row & 7)) << 4));
            ae[jt] = mfma16(qa[ks], kb, ae[jt]);
        }
    }

    // ---- softmax: e = E/8 + log(fm+1e-6) ----
    const float* mrow = mask + (size_t)b * L + jbase;
    float pw8[8];
#pragma unroll
    for (int jt = 0; jt < 8; ++jt) {
        const int j = l15 + jt * 16;
        pw8[jt] = (n == 0 && j < 64) ? 0.f : mrow[j];
    }
    const int ii0 = w * 16 + g * 4;
#pragma unroll
    for (int jt = 0; jt < 8; ++jt) {
        const int j = l15 + jt * 16;
#pragma unroll
        for (int r = 0; r < 4; ++r) {
            const float fm = (j >= ii0 + r && j < ii0 + r + 64) ? pw8[jt] : 0.f;
            ae[jt][r] = ae[jt][r] * 0.125f + __logf(fm + 1e-6f);
        }
    }
    f32x4 mx, inv;
#pragma unroll
    for (int r = 0; r < 4; ++r) {
        float m = ae[0][r];
#pragma unroll
        for (int jt = 1; jt < 8; ++jt) m = fmaxf(m, ae[jt][r]);
        m = fmaxf(m, __shfl_xor(m, 1));
        m = fmaxf(m, __shfl_xor(m, 2));
        m = fmaxf(m, __shfl_xor(m, 4));
        m = fmaxf(m, __shfl_xor(m, 8));
        mx[r] = m;
    }
    f32x4 sum = {0.f, 0.f, 0.f, 0.f};
#pragma unroll
    for (int jt = 0; jt < 8; ++jt)
#pragma unroll
        for (int r = 0; r < 4; ++r) {
            const float p = __expf(ae[jt][r] - mx[r]);
            ae[jt][r] = p;
            sum[r] += p;
        }
#pragma unroll
    for (int r = 0; r < 4; ++r) {
        float s = sum[r];
        s += __shfl_xor(s, 1);
        s += __shfl_xor(s, 2);
        s += __shfl_xor(s, 4);
        s += __shfl_xor(s, 8);
        inv[r] = 1.0f / s;
    }
#pragma unroll
    for (int jt = 0; jt < 8; ++jt) {
        const int j = l15 + jt * 16;
#pragma unroll
        for (int r = 0; r < 4; ++r) {
            const float fm = (j >= ii0 + r && j < ii0 + r + 64) ? pw8[jt] : 0.f;
            const float p = ae[jt][r] * inv[r] * fm;
            const int lrow = w * 16 + g * 4 + r;
            *(unsigned short*)((char*)ps + lrow * 256 +
                (((j >> 3) ^ (lrow & 7)) << 4) + (j & 7) * 2) = f2bfu(p);
        }
    }

    // ---- AO^T[l][c] = att[l][:] x v[c][:] ----
    f32x4 ao[4];
#pragma unroll
    for (int ct = 0; ct < 4; ++ct) ao[ct] = (f32x4){0.f, 0.f, 0.f, 0.f};
#pragma unroll
    for (int ks = 0; ks < 4; ++ks) {
        const int arow = w * 16 + l15;
        const int aq_ = ks * 4 + g;
        const bf16x8 pa = *(const bf16x8*)((char*)ps + arow * 256 + ((aq_ ^ (arow & 7)) << 4));
#pragma unroll
        for (int ct = 0; ct < 4; ++ct) {
            const int vrow = ct * 16 + l15;
            const bf16x8 vb = *(const bf16x8*)((char*)vs + vrow * 256 + ((aq_ ^ (vrow & 7)) << 4));
            ao[ct] = mfma16(pa, vb, ao[ct]);
        }
    }
#pragma unroll
    for (int ct = 0; ct < 4; ++ct)
#pragma unroll
        for (int r = 0; r < 4; ++r) {
            const int lr = w * 16 + g * 4 + r;
            const int c  = ct * 16 + l15;
            *(unsigned short*)((char*)aos + lr * 128 +
                (((c >> 3) ^ (lr & 7)) << 4) + (c & 7) * 2) = f2bfu(fmaxf(ao[ct][r], 0.f));
        }
    __syncthreads();

    // ---- out = Wo @ relu(AO) + bo, * mask ----
    f32x4 mvv;
#pragma unroll
    for (int lt = 0; lt < 4; ++lt)
        mvv[lt] = mask[(size_t)b * L + n * 64 + lt * 16 + l15];

    bf16x8 bbs[8];
#pragma unroll
    for (int ks = 0; ks < 2; ++ks)
#pragma unroll
        for (int lt = 0; lt < 4; ++lt) {
            const int brow = lt * 16 + l15;
            bbs[ks * 4 + lt] = *(const bf16x8*)((char*)aos + brow * 128 +
                (((ks * 4 + g) ^ (brow & 7)) << 4));
        }

#pragma unroll 1
    for (int ot = 0; ot < 4; ++ot) {
        const int orow = ot * 64 + w * 16 + l15;
        bf16x8 wa[2];
#pragma unroll
        for (int ks = 0; ks < 2; ++ks)
            wa[ks] = *(const bf16x8*)(wob + (size_t)orow * 64 + ks * 32 + g * 8);
        f32x4 acw[4];
#pragma unroll
        for (int lt = 0; lt < 4; ++lt) acw[lt] = (f32x4){0.f, 0.f, 0.f, 0.f};
#pragma unroll
        for (int ks = 0; ks < 2; ++ks)
#pragma unroll
            for (int lt = 0; lt < 4; ++lt)
                acw[lt] = mfma16(wa[ks], bbs[ks * 4 + lt], acw[lt]);
        const f32x4 bo4 = *(const f32x4*)(bo + ot * 64 + w * 16 + g * 4);
#pragma unroll
        for (int lt = 0; lt < 4; ++lt) {
            const int pos = n * 64 + lt * 16 + l15;
#pragma unroll
            for (int r = 0; r < 4; ++r) {
                const int o = ot * 64 + w * 16 + g * 4 + r;
                outp[((size_t)b * C + o) * L + pos] = (acw[lt][r] + bo4[r]) * mvv[lt];
            }
        }
    }
}

// ---------------------------------------------------------------------------
extern "C" void kernel_launch(void* const* d_in, const int* in_sizes, int n_in,
                              void* d_out, int out_size, void* d_ws, size_t ws_size,
                              hipStream_t stream) {
    const float* x1   = (const float*)d_in[0];
    const float* x2   = (const float*)d_in[1];
    const float* mask = (const float*)d_in[2];
    const float* Wq   = (const float*)d_in[3];
    const float* bq   = (const float*)d_in[4];
    const float* Wk   = (const float*)d_in[5];
    const float* bk   = (const float*)d_in[6];
    const float* Wv   = (const float*)d_in[7];
    const float* bv   = (const float*)d_in[8];
    const float* Wo   = (const float*)d_in[9];
    const float* bo   = (const float*)d_in[10];
    float* out = (float*)d_out;

    unsigned short* ws = (unsigned short*)d_ws;
    const size_t PL = (size_t)B * L * CH;
    unsigned short* qt = ws;
    unsigned short* kt = qt + PL;
    unsigned short* vt = kt + PL;
    unsigned short* wb = vt + PL;   // [4][16384] bf16 weights
    const size_t need = (3 * PL + 4 * 16384) * sizeof(unsigned short);
    if (ws_size < need) {
        hipMemsetAsync(d_out, 0, (size_t)out_size * sizeof(float), stream);
        return;
    }

    wcvt_kernel<<<dim3(16, 4), 256, 0, stream>>>(Wq, Wk, Wv, Wo, wb);

    qkv_mfma<<<dim3(L / 64, B), 256, 0, stream>>>(
        x1, x2, wb, wb + 16384, wb + 2 * 16384, bq, bk, bv, qt, kt, vt);

    attn_mfma<<<dim3(NB * B), 256, 0, stream>>>(
        qt, kt, vt, mask, wb + 3 * 16384, bo, out);
}